// Round 1
// baseline (128.938 us; speedup 1.0000x reference)
//
#include <hip/hip_runtime.h>

typedef __attribute__((ext_vector_type(4))) int int4v;

// ---------------------------------------------------------------------------
// Pack int32 (values in int8 range) -> int8, 4 elems/thread-iter.
__global__ __launch_bounds__(256) void pack_i8_kernel(
    const int* __restrict__ src, int* __restrict__ dst, int n4)
{
    int i = blockIdx.x * blockDim.x + threadIdx.x;
    const int stride = gridDim.x * blockDim.x;
    for (; i < n4; i += stride) {
        int4v v = ((const int4v*)src)[i];
        int p = (v.x & 255) | ((v.y & 255) << 8) | ((v.z & 255) << 16) | ((v.w & 255) << 24);
        dst[i] = p;
    }
}

// ---------------------------------------------------------------------------
// 128x128 tile, BK=128 (bytes == i8 elems), 4 waves each computing 64x64.
// global_load_lds width-16 staging with inverse-swizzled global source;
// XOR-swizzled ds_read_b128 (col ^= (row&7)<<4) for conflict-free reads.
__global__ __launch_bounds__(256) void gemm_i8_kernel(
    const char* __restrict__ A8,   // [M][K] int8
    const char* __restrict__ B8,   // [N][K] int8  (weight, row n = out col)
    const float* __restrict__ scale,
    const int* __restrict__ bias,
    float* __restrict__ out,
    int M, int N, int K)
{
    __shared__ __attribute__((aligned(16))) char lsA[128 * 128];
    __shared__ __attribute__((aligned(16))) char lsB[128 * 128];

    const int tid  = threadIdx.x;
    const int lane = tid & 63;
    const int wid  = tid >> 6;

    const int m0 = blockIdx.y * 128;
    const int n0 = blockIdx.x * 128;

    const int wr = wid >> 1, wc = wid & 1;
    const int wm0 = wr * 64, wn0 = wc * 64;

    // staging geometry: each wave stages 32 rows (4 issues x 8 rows x 128B)
    const int r8 = lane >> 3;                  // 0..7 (row within 8-row issue)
    const int c8 = lane & 7;                   // 0..7 (16B slot)
    const int swzcol = ((c8 ^ r8) << 4);       // inverse-swizzled source col
    const int stRow = wid * 32;

    int4v acc[4][4];
#pragma unroll
    for (int i = 0; i < 4; ++i)
#pragma unroll
        for (int j = 0; j < 4; ++j)
            acc[i][j] = (int4v){0, 0, 0, 0};

    const int nkt = K >> 7;                    // K / 128
    for (int t = 0; t < nkt; ++t) {
        const int k0 = t << 7;
#pragma unroll
        for (int j = 0; j < 4; ++j) {
            const char* srcA = A8 + (size_t)(m0 + stRow + j * 8 + r8) * K + (k0 + swzcol);
            const char* srcB = B8 + (size_t)(n0 + stRow + j * 8 + r8) * K + (k0 + swzcol);
            __builtin_amdgcn_global_load_lds(
                (const __attribute__((address_space(1))) void*)srcA,
                (__attribute__((address_space(3))) void*)(lsA + (stRow + j * 8) * 128),
                16, 0, 0);
            __builtin_amdgcn_global_load_lds(
                (const __attribute__((address_space(1))) void*)srcB,
                (__attribute__((address_space(3))) void*)(lsB + (stRow + j * 8) * 128),
                16, 0, 0);
        }
        __syncthreads();

#pragma unroll
        for (int kk = 0; kk < 2; ++kk) {
            int4v af[4], bf[4];
#pragma unroll
            for (int i = 0; i < 4; ++i) {
                const int rowA = wm0 + i * 16 + (lane & 15);
                const int col  = (kk * 64 + (lane >> 4) * 16) ^ ((rowA & 7) << 4);
                af[i] = *(const int4v*)(lsA + rowA * 128 + col);
                const int rowB = wn0 + i * 16 + (lane & 15);
                bf[i] = *(const int4v*)(lsB + rowB * 128 + col);
            }
#pragma unroll
            for (int i = 0; i < 4; ++i)
#pragma unroll
                for (int j = 0; j < 4; ++j)
                    acc[i][j] = __builtin_amdgcn_mfma_i32_16x16x64_i8(af[i], bf[j], acc[i][j], 0, 0, 0);
        }
        __syncthreads();
    }

    // epilogue: out = (acc + bias[col]) * scale[col]
    const int lc = lane & 15;
    const int lq = lane >> 4;
    float scl[4];
    int   bsv[4];
#pragma unroll
    for (int j = 0; j < 4; ++j) {
        const int col = n0 + wn0 + j * 16 + lc;
        scl[j] = scale[col];
        bsv[j] = bias[col];
    }
#pragma unroll
    for (int i = 0; i < 4; ++i) {
        const int rowb = m0 + wm0 + i * 16 + lq * 4;
#pragma unroll
        for (int j = 0; j < 4; ++j) {
            const int col = n0 + wn0 + j * 16 + lc;
#pragma unroll
            for (int r = 0; r < 4; ++r) {
                out[(size_t)(rowb + r) * N + col] = (float)(acc[i][j][r] + bsv[j]) * scl[j];
            }
        }
    }
}

// ---------------------------------------------------------------------------
// Safety fallback if d_ws is too small for packed operands (slow but correct).
__global__ __launch_bounds__(256) void naive_kernel(
    const int* __restrict__ x, const int* __restrict__ w,
    const float* __restrict__ scale, const int* __restrict__ bias,
    float* __restrict__ out, int M, int N, int K)
{
    size_t idx = (size_t)blockIdx.x * blockDim.x + threadIdx.x;
    const size_t total = (size_t)M * N;
    const size_t stride = (size_t)gridDim.x * blockDim.x;
    for (; idx < total; idx += stride) {
        const int m = (int)(idx / N), n = (int)(idx % N);
        int acc = 0;
        for (int k = 0; k < K; ++k) acc += x[(size_t)m * K + k] * w[(size_t)n * K + k];
        out[idx] = (float)(acc + bias[n]) * scale[n];
    }
}

// ---------------------------------------------------------------------------
extern "C" void kernel_launch(void* const* d_in, const int* in_sizes, int n_in,
                              void* d_out, int out_size, void* d_ws, size_t ws_size,
                              hipStream_t stream)
{
    const int*   x     = (const int*)d_in[0];
    const int*   w     = (const int*)d_in[1];
    const float* scale = (const float*)d_in[2];
    const int*   bias  = (const int*)d_in[3];
    float*       out   = (float*)d_out;

    const int N = in_sizes[2];
    const int K = in_sizes[1] / N;
    const int M = in_sizes[0] / K;

    const size_t needA = (size_t)M * K;
    const size_t needB = (size_t)N * K;

    if (ws_size < needA + needB || (M % 128) || (N % 128) || (K % 128)) {
        const int blocks = 8192;
        naive_kernel<<<blocks, 256, 0, stream>>>(x, w, scale, bias, out, M, N, K);
        return;
    }

    char* x8 = (char*)d_ws;
    char* w8 = x8 + needA;

    pack_i8_kernel<<<4096, 256, 0, stream>>>(x, (int*)x8, (M * K) >> 2);
    pack_i8_kernel<<<4096, 256, 0, stream>>>(w, (int*)w8, (N * K) >> 2);

    dim3 grid(N / 128, M / 128);
    gemm_i8_kernel<<<grid, 256, 0, stream>>>(x8, w8, scale, bias, out, M, N, K);
}

// Round 2
// 127.908 us; speedup vs baseline: 1.0081x; 1.0081x over previous
//
#include <hip/hip_runtime.h>

typedef __attribute__((ext_vector_type(4))) int int4v;

#define AS1 __attribute__((address_space(1)))
#define AS3 __attribute__((address_space(3)))

#define BAR()   __builtin_amdgcn_s_barrier()
#define LGKM0() asm volatile("s_waitcnt lgkmcnt(0)" ::: "memory")

// stage one 64-row x 128B unit: LDS dest linear, global source inverse-swizzled
// (rule #21: source permutation == read permutation, col ^= (row&7)<<4)
#define STG_A(sb, rowbase, k0) \
    __builtin_amdgcn_global_load_lds( \
        (const AS1 void*)(aSrcBase + (size_t)(rowbase) * K + (k0)), \
        (AS3 void*)(ldsDestA + (sb) + (rowbase) * 128), 16, 0, 0)
#define STG_B(sb, rowbase, k0) \
    __builtin_amdgcn_global_load_lds( \
        (const AS1 void*)(bSrcBase + (size_t)(rowbase) * K + (k0)), \
        (AS3 void*)(ldsDestB + (sb) + (rowbase) * 128), 16, 0, 0)

#define LDA(mq, sb) \
    { _Pragma("unroll") for (int m = 0; m < 4; ++m) { \
        const int rb = (sb) + ((aRow0 + ((mq) << 6) + (m << 4)) << 7); \
        a[m][0] = *(const int4v*)(ls + rb + colx0); \
        a[m][1] = *(const int4v*)(ls + rb + colx1); } }

#define LDB(nq, sb) \
    { _Pragma("unroll") for (int n = 0; n < 2; ++n) { \
        const int rb = (sb) + 32768 + ((bRow0 + ((nq) << 5) + (n << 4)) << 7); \
        b[(nq)*2 + n][0] = *(const int4v*)(ls + rb + colx0); \
        b[(nq)*2 + n][1] = *(const int4v*)(ls + rb + colx1); } }

#define MMA(mq, nq) \
    { __builtin_amdgcn_s_setprio(1); \
      _Pragma("unroll") for (int m = 0; m < 4; ++m) \
      _Pragma("unroll") for (int n = 0; n < 2; ++n) { \
        acc[(mq)*4 + m][(nq)*2 + n] = __builtin_amdgcn_mfma_i32_16x16x64_i8( \
            a[m][0], b[(nq)*2 + n][0], acc[(mq)*4 + m][(nq)*2 + n], 0, 0, 0); \
        acc[(mq)*4 + m][(nq)*2 + n] = __builtin_amdgcn_mfma_i32_16x16x64_i8( \
            a[m][1], b[(nq)*2 + n][1], acc[(mq)*4 + m][(nq)*2 + n], 0, 0, 0); } \
      __builtin_amdgcn_s_setprio(0); }

// ---------------------------------------------------------------------------
// Pack both int32->int8 operands in one launch (memory-bound).
__global__ __launch_bounds__(256) void pack_both_kernel(
    const int* __restrict__ x, const int* __restrict__ w,
    int* __restrict__ x8, int* __restrict__ w8, int n4x, int n4w)
{
    int i = blockIdx.x * blockDim.x + threadIdx.x;
    const int stride = gridDim.x * blockDim.x;
    const int tot = n4x + n4w;
    for (; i < tot; i += stride) {
        const bool isx = i < n4x;
        const int4v v = isx ? ((const int4v*)x)[i] : ((const int4v*)w)[i - n4x];
        const int p = (v.x & 255) | ((v.y & 255) << 8) | ((v.z & 255) << 16) | ((v.w & 255) << 24);
        if (isx) x8[i] = p; else w8[i - n4x] = p;
    }
}

// ---------------------------------------------------------------------------
// 256x256 tile, BK=128 i8, 8 waves (2Mx4N), 8-phase counted-vmcnt schedule.
// LDS: slot s at s*65536: [A 256x128 | B 256x128]; double buffer = 128 KiB.
__global__ __launch_bounds__(512, 2) void gemm_i8_256(
    const char* __restrict__ A8, const char* __restrict__ B8,
    const float* __restrict__ scale, const int* __restrict__ bias,
    float* __restrict__ out, int M, int N, int K, int nwg_n)
{
    extern __shared__ __attribute__((aligned(16))) char ls[];

    const int tid  = threadIdx.x;
    const int lane = tid & 63;
    const int wid  = tid >> 6;
    const int wr   = wid >> 2;      // 0..1 (M)
    const int wc   = wid & 3;       // 0..3 (N)
    const int l15  = lane & 15;
    const int hi16 = lane >> 4;

    // bijective XCD swizzle (T1)
    int wg = blockIdx.x;
    {
        const int nwg = gridDim.x;
        const int q = nwg >> 3, r = nwg & 7;
        const int x = wg & 7, lq = wg >> 3;
        wg = (x < r ? x * (q + 1) : r * (q + 1) + (x - r) * q) + lq;
    }
    const int m0 = (wg / nwg_n) << 8;
    const int n0 = (wg % nwg_n) << 8;

    // per-thread swizzled read columns for kk=0,1 (T2)
    const int sw    = (l15 & 7) << 4;
    const int colx0 = ((hi16 << 4)) ^ sw;
    const int colx1 = (64 + (hi16 << 4)) ^ sw;
    const int aRow0 = (wr << 7) + l15;
    const int bRow0 = (wc << 6) + l15;

    // staging addresses (thread t covers row t>>3, 16B slot t&7 of each unit)
    const int srow  = tid >> 3;
    const int sslot = tid & 7;
    const int scol  = ((sslot ^ (srow & 7)) << 4);
    const char* aSrcBase = A8 + (size_t)(m0 + srow) * K + scol;
    const char* bSrcBase = B8 + (size_t)(n0 + srow) * K + scol;
    char* ldsDestA = ls + srow * 128 + (sslot << 4);
    char* ldsDestB = ls + 32768 + srow * 128 + (sslot << 4);

    int4v acc[8][4];
#pragma unroll
    for (int i = 0; i < 8; ++i)
#pragma unroll
        for (int j = 0; j < 4; ++j)
            acc[i][j] = (int4v){0, 0, 0, 0};

    int4v a[4][2], b[4][2];

    const int nkt = K >> 7;         // K/128, even (K%256==0 guaranteed by host)
    const int nit = nkt >> 1;

    // prologue: tile0 (8 units) -> slot0; tile1 first 6 units -> slot1
    STG_A(0, 0, 0);   STG_A(0, 128, 0);
    STG_A(0, 64, 0);  STG_A(0, 192, 0);
    STG_B(0, 0, 0);   STG_B(0, 64, 0);
    STG_B(0, 128, 0); STG_B(0, 192, 0);
    STG_A(65536, 0, 128); STG_A(65536, 128, 128);
    STG_B(65536, 0, 128); STG_B(65536, 64, 128);
    STG_B(65536, 128, 128); STG_B(65536, 192, 128);
    asm volatile("s_waitcnt vmcnt(6)" ::: "memory");
    BAR();

#pragma unroll 1
    for (int it = 0; it < nit; ++it) {
        const int kO1 = (2 * it + 1) << 7;      // odd tile in slot1 (last 2 units)
        const int tE = 2 * it + 2, tO = 2 * it + 3;
        const int kE = tE << 7, kO = tO << 7;
        const bool ok = tE < nkt;               // nkt even => okE == okO

        // g0: (mq0,nq0) slot0 | stage odd-tile uA2,uA3 -> slot1
        LDA(0, 0); LDB(0, 0);
        STG_A(65536, 64, kO1); STG_A(65536, 192, kO1);
        BAR(); LGKM0();
        MMA(0, 0);
        BAR();

        // g1: (mq0,nq1) slot0 | stage tE uA0,uA1 -> slot0
        LDB(1, 0);
        if (ok) { STG_A(0, 0, kE); STG_A(0, 128, kE); }
        BAR(); LGKM0();
        MMA(0, 1);
        BAR();

        // g2: (mq1,nq1) slot0 | stage tE uB0,uB1
        LDA(1, 0);
        if (ok) { STG_B(0, 0, kE); STG_B(0, 64, kE); }
        BAR(); LGKM0();
        MMA(1, 1);
        BAR();

        // g3: (mq1,nq0) slot0 | stage tE uB2,uB3 | gate slot1
        if (ok) { STG_B(0, 128, kE); STG_B(0, 192, kE); }
        BAR(); LGKM0();
        MMA(1, 0);
        if (ok) { asm volatile("s_waitcnt vmcnt(6)" ::: "memory"); }
        else    { asm volatile("s_waitcnt vmcnt(0)" ::: "memory"); }
        BAR();

        // g4: (mq0,nq0) slot1 | stage tE uA2,uA3
        LDA(0, 65536); LDB(0, 65536);
        if (ok) { STG_A(0, 64, kE); STG_A(0, 192, kE); }
        BAR(); LGKM0();
        MMA(0, 0);
        BAR();

        // g5: (mq0,nq1) slot1 | stage tO uA0,uA1 -> slot1
        LDB(1, 65536);
        if (ok) { STG_A(65536, 0, kO); STG_A(65536, 128, kO); }
        BAR(); LGKM0();
        MMA(0, 1);
        BAR();

        // g6: (mq1,nq1) slot1 | stage tO uB0,uB1
        LDA(1, 65536);
        if (ok) { STG_B(65536, 0, kO); STG_B(65536, 64, kO); }
        BAR(); LGKM0();
        MMA(1, 1);
        BAR();

        // g7: (mq1,nq0) slot1 | stage tO uB2,uB3 | gate slot0
        if (ok) { STG_B(65536, 128, kO); STG_B(65536, 192, kO); }
        BAR(); LGKM0();
        MMA(1, 0);
        if (ok) { asm volatile("s_waitcnt vmcnt(6)" ::: "memory"); }
        else    { asm volatile("s_waitcnt vmcnt(0)" ::: "memory"); }
        BAR();
    }

    // epilogue: out = (acc + bias[col]) * scale[col]
    float scl[4]; int bsv[4];
#pragma unroll
    for (int nj = 0; nj < 4; ++nj) {
        const int col = n0 + (wc << 6) + (nj << 4) + l15;
        scl[nj] = scale[col];
        bsv[nj] = bias[col];
    }
#pragma unroll
    for (int mi = 0; mi < 8; ++mi) {
        const int rowb = m0 + (wr << 7) + (mi << 4) + (hi16 << 2);
#pragma unroll
        for (int nj = 0; nj < 4; ++nj) {
            const int col = n0 + (wc << 6) + (nj << 4) + l15;
            float* o = out + (size_t)rowb * N + col;
#pragma unroll
            for (int r = 0; r < 4; ++r)
                o[(size_t)r * N] = (float)(acc[mi][nj][r] + bsv[nj]) * scl[nj];
        }
    }
}

// ---------------------------------------------------------------------------
// Safety fallback (slow but correct) for shapes the tiled path can't handle.
__global__ __launch_bounds__(256) void naive_kernel(
    const int* __restrict__ x, const int* __restrict__ w,
    const float* __restrict__ scale, const int* __restrict__ bias,
    float* __restrict__ out, int M, int N, int K)
{
    size_t idx = (size_t)blockIdx.x * blockDim.x + threadIdx.x;
    const size_t total = (size_t)M * N;
    const size_t stride = (size_t)gridDim.x * blockDim.x;
    for (; idx < total; idx += stride) {
        const int m = (int)(idx / N), n = (int)(idx % N);
        int acc = 0;
        for (int k = 0; k < K; ++k) acc += x[(size_t)m * K + k] * w[(size_t)n * K + k];
        out[idx] = (float)(acc + bias[n]) * scale[n];
    }
}

// ---------------------------------------------------------------------------
extern "C" void kernel_launch(void* const* d_in, const int* in_sizes, int n_in,
                              void* d_out, int out_size, void* d_ws, size_t ws_size,
                              hipStream_t stream)
{
    const int*   x     = (const int*)d_in[0];
    const int*   w     = (const int*)d_in[1];
    const float* scale = (const float*)d_in[2];
    const int*   bias  = (const int*)d_in[3];
    float*       out   = (float*)d_out;

    const int N = in_sizes[2];
    const int K = in_sizes[1] / N;
    const int M = in_sizes[0] / K;

    const size_t needA = (size_t)M * K;
    const size_t needB = (size_t)N * K;

    if (ws_size < needA + needB || (M % 256) || (N % 256) || (K % 256)) {
        naive_kernel<<<8192, 256, 0, stream>>>(x, w, scale, bias, out, M, N, K);
        return;
    }

    char* x8 = (char*)d_ws;
    char* w8 = x8 + needA;

    pack_both_kernel<<<2048, 256, 0, stream>>>(x, w, (int*)x8, (int*)w8,
                                               (int)(needA >> 2), (int)(needB >> 2));

    hipFuncSetAttribute((const void*)gemm_i8_256,
                        hipFuncAttributeMaxDynamicSharedMemorySize, 131072);

    const int nwg_n = N / 256;
    const int nwg = (M / 256) * nwg_n;
    gemm_i8_256<<<nwg, 512, 131072, stream>>>(x8, w8, scale, bias, out, M, N, K, nwg_n);
}